// Round 12
// baseline (284.916 us; speedup 1.0000x reference)
//
#include <hip/hip_runtime.h>

using u16 = unsigned short;
using u32 = unsigned int;
typedef __attribute__((ext_vector_type(8))) short bf16x8;
typedef __attribute__((ext_vector_type(4))) float f32x4;

// ---------- posit(8,1) round-to-nearest (float core, verified bit-exact on HW) ----------
__device__ __forceinline__ float posit_q(float x) {
    float a = __builtin_fabsf(x);
    u32 u = __float_as_uint(a);
    int logx = (int)(u >> 23) - 127;
    logx = logx < -60 ? -60 : (logx > 60 ? 60 : logx);
    float frac = __uint_as_float((u & 0x007fffffu) | 0x3f800000u);  // [1,2)
    int k = logx >> 1;                            // floor(logx/2), es=1
    int rl = (k >= 0) ? (k + 2) : (1 - k);        // regime length
    int fb = 6 - rl; fb = fb < 0 ? 0 : fb;        // fraction bits, <=4
    float step = (float)(1 << fb);
    float q = rintf(frac * step) * __uint_as_float((u32)(127 + logx - fb) << 23);
    q = fminf(fmaxf(q, 0x1p-12f), 0x1p12f);
    return (a > 0.0f) ? copysignf(q, x) : 0.0f;
}

__device__ __forceinline__ float b2f(u16 v) { return __uint_as_float((u32)v << 16); }
__device__ __forceinline__ u16 f2b(float f) { return (u16)(__float_as_uint(f) >> 16); }  // exact for posit values

// ---------- Dekker-LUT posit quantizer (exact RNE onto the posit grid; verified R8) ----------
__device__ __forceinline__ void lut_init(int tid, float* lut) {
    if (tid < 256) {
        int e = tid - 127;
        float m = 0.f;
        if (e >= -12 && e <= 12) {
            int k = e >> 1;
            int rl = max(k + 2, 1 - k);
            int fb = max(6 - rl, 0);
            m = __uint_as_float((u32)(150 + e - fb) << 23) * 1.5f;  // 1.5*2^(23+e-fb)
        }
        lut[tid] = m;
    }
}
__device__ __forceinline__ u32 pq_pos_raw(float x, const float* __restrict__ lut) {  // x >= 0
    u32 u = __float_as_uint(x);
    float c = lut[u >> 23];
    float q = (x + c) - c;
    q = fminf(fmaxf(q, 0x1p-12f), 0x1p12f);
    return u == 0u ? 0u : __float_as_uint(q);
}

// ---------- kernel 1: quantize small weights (w1, w2frag, fc2) ----------
__global__ __launch_bounds__(256) void prep_kernel(
    const float* __restrict__ w1, const float* __restrict__ w2,
    const float* __restrict__ fw2,
    float* __restrict__ w1q, u16* __restrict__ w2frag, float* __restrict__ fc2wq) {
    int i = blockIdx.x * 256 + threadIdx.x;
    if (i < 288)  w1q[i]   = posit_q(w1[i]);
    if (i < 1280) fc2wq[i] = posit_q(fw2[i]);
    if (i < 18432) {
        int e = i & 7, lane = (i >> 3) & 63, c9 = i >> 9;
        int kc = c9 % 9, nt = c9 / 9;
        int n = nt * 16 + (lane & 15);
        int ci = ((lane >> 4) << 3) + e;
        w2frag[i] = f2b(posit_q(w2[n * 288 + ci * 9 + kc]));  // w2 flat [n][ci][kh][kw]
    }
}

// ---------- kernel 1b: quantize fc1 weights into FRAG-LINEAR layout ----------
// fc1wqF[nt(8)][kk(288)][lane(64)][e(8)]: holds pq(fw1)[n][k], n = nt*16 + (lane&15),
// k = kk*32 + (lane>>4)*8 + e  -> fc1_part B-loads become dense 1 KB wave-loads.
__global__ __launch_bounds__(256) void prep2_kernel(
    const float* __restrict__ fw1, u16* __restrict__ fc1wqF) {
    int i = blockIdx.x * 256 + threadIdx.x;       // grid exactly covers 1179648
    int e = i & 7, lane = (i >> 3) & 63, c = i >> 9;
    int kk = c % 288, nt = c / 288;
    int n = nt * 16 + (lane & 15);
    int k = kk * 32 + ((lane >> 4) << 3) + e;
    fc1wqF[i] = f2b(posit_q(fw1[(size_t)n * 9216 + k]));
}

// ---------- kernel 2: fused pq(x) + conv1 + relu + pq + conv2(MFMA) + pool + bias + relu + pq ----------
// R8 config (measured ~146 us, VGPR 52): 512 threads, (512,4), LDS ~67 KB -> 2 blocks/CU.
#define PLS 5416
__global__ __launch_bounds__(512, 4) void conv_fused_kernel(
    const float* __restrict__ x, const float* __restrict__ w1q, const float* __restrict__ b1,
    const u16* __restrict__ w2frag, const float* __restrict__ b2, u16* __restrict__ pooled) {
    __shared__ __align__(16) float sX[784];           // 3136 B
    __shared__ __align__(16) u16 sH1[4 * PLS];        // 43328 B
    __shared__ __align__(16) u16 sPool[64 * 152];     // 19456 B
    __shared__ float sLut[256];                       // 1024 B (total ~67 KB -> 2 blocks/CU)
    int img = blockIdx.x, tid = threadIdx.x;
    int wave = tid >> 6, lane = tid & 63;
    int col = lane & 15, quad = lane >> 4;

    lut_init(tid, sLut);

    // phase 0: pq input image -> LDS
    for (int i = tid; i < 784; i += 512) sX[i] = posit_q(x[(size_t)img * 784 + i]);

    // conv1 weights for this thread's oc pair (registers)
    int ocp = tid & 15;
    float wreg[18];
#pragma unroll
    for (int j = 0; j < 18; ++j) wreg[j] = w1q[ocp * 18 + j];
    float bias0 = b1[ocp * 2], bias1 = b1[ocp * 2 + 1];

    __syncthreads();

    // phase 1: conv1 (+bias+relu+pq) -> sH1 planes. thread = (pgrp = tid>>4 in 0..31, ocp).
    int pgrp = tid >> 4;
    u16* h1dst = &sH1[(ocp >> 2) * PLS + 2 * (ocp & 3)];
    for (int it = 0; it < 22; ++it) {
        int p = it * 32 + pgrp;
        if (p < 676) {
            int y = p / 26, xx = p - y * 26;
            const float* px = &sX[y * 28 + xx];
            float in9[9];
#pragma unroll
            for (int r = 0; r < 3; ++r)
#pragma unroll
                for (int c = 0; c < 3; ++c) in9[r * 3 + c] = px[r * 28 + c];
            float a0 = bias0, a1 = bias1;
#pragma unroll
            for (int j = 0; j < 9; ++j) {
                a0 = fmaf(wreg[j], in9[j], a0);
                a1 = fmaf(wreg[9 + j], in9[j], a1);
            }
            u32 r0 = pq_pos_raw(fmaxf(a0, 0.f), sLut);
            u32 r1 = pq_pos_raw(fmaxf(a1, 0.f), sLut);
            *(u32*)&h1dst[p * 8] = (r0 >> 16) | (r1 & 0xFFFF0000u);
        }
    }

    // conv2 B-frags for this wave's n-pair
    __syncthreads();
    int npair = wave & 1, mq = wave >> 1;
    bf16x8 bfrag[2][9];
#pragma unroll
    for (int j = 0; j < 2; ++j)
#pragma unroll
        for (int kc = 0; kc < 9; ++kc)
            bfrag[j][kc] = *(const bf16x8*)(w2frag + (((npair * 2 + j) * 9 + kc) * 64 + lane) * 8);
    float cb0 = b2[(npair * 2) * 16 + col];
    float cb1 = b2[(npair * 2 + 1) * 16 + col];
    int poolb0 = ((npair * 2) * 16 + col) * 152;
    int poolb1 = ((npair * 2 + 1) * 16 + col) * 152;
    const u16* aplane = &sH1[quad * PLS];

    // phase 2: conv2 MFMA + pool(max) + bias + relu + pq. Wave: m-tiles mq*9..mq*9+8, 2 n-tiles.
    for (int t = 0; t < 9; ++t) {
        int mt = mq * 9 + t;
        int m = mt * 16 + col;                  // pool-permuted m (A-row = lane&15)
        int pp = m >> 2, wi = m & 3;
        int py = pp / 12, px_ = pp - py * 12;
        int oh = 2 * py + (wi >> 1), ow = 2 * px_ + (wi & 1);
        const u16* ap = aplane + (oh * 26 + ow) * 8;
        f32x4 acc0 = {0.f, 0.f, 0.f, 0.f}, acc1 = {0.f, 0.f, 0.f, 0.f};
#pragma unroll
        for (int kc = 0; kc < 9; ++kc) {
            int kh = kc / 3, kw = kc - kh * 3;
            bf16x8 af = *(const bf16x8*)(ap + (kh * 26 + kw) * 8);
            acc0 = __builtin_amdgcn_mfma_f32_16x16x32_bf16(af, bfrag[0][kc], acc0, 0, 0, 0);
            acc1 = __builtin_amdgcn_mfma_f32_16x16x32_bf16(af, bfrag[1][kc], acc1, 0, 0, 0);
        }
        // C/D: row = quad*4+reg -> lane's 4 regs = one 2x2 pool window; max commutes exactly
        float mx0 = fmaxf(fmaxf(acc0[0], acc0[1]), fmaxf(acc0[2], acc0[3]));
        float mx1 = fmaxf(fmaxf(acc1[0], acc1[1]), fmaxf(acc1[2], acc1[3]));
        sPool[poolb0 + mt * 4 + quad] = (u16)(pq_pos_raw(fmaxf(mx0 + cb0, 0.f), sLut) >> 16);
        sPool[poolb1 + mt * 4 + quad] = (u16)(pq_pos_raw(fmaxf(mx1 + cb1, 0.f), sLut) >> 16);
    }
    __syncthreads();

    // phase 3: coalesced writeout, c-major (fc1 K layout)
    for (int u = tid; u < 1152; u += 512) {
        int c = u / 18, g = u - c * 18;
        uint4 v = *(const uint4*)&sPool[c * 152 + g * 8];
        *(uint4*)(pooled + (size_t)img * 9216 + c * 144 + g * 8) = v;
    }
}

// ---------- kernel 3a: fc1 partial GEMM, K split 4 ways — all-coalesced v2 ----------
// A staged to LDS (coalesced uint4, frags via ds_read_b128, row stride 2328 u16: 16B-aligned,
// 2-lanes/bank = free); B from frag-linear fc1wqF (dense 1 KB wave-loads). sAcc unioned over sA.
#define AS 2328
__global__ __launch_bounds__(512, 4) void fc1_part_kernel(const u16* __restrict__ pooled,
    const u16* __restrict__ fc1wqF, float* __restrict__ part) {
    __shared__ __align__(16) char smem[16 * AS * 2];   // 74496 B -> 2 blocks/CU
    u16* sA = (u16*)smem;
    float* sAcc = (float*)smem;                        // reused AFTER barrier (16*132*4 floats = 33792 B)
    int blk = blockIdx.x, tid = threadIdx.x;
    int mb = blk >> 2, ks = blk & 3;
    int wave = tid >> 6, lane = tid & 63;
    int row = lane & 15, quad = lane >> 4;

    // stage A-tile: rows mb*16..+15, K-slice ks*2304..+2303 (73728 B, fully coalesced)
    {
        const u16* src = pooled + (size_t)mb * 16 * 9216 + ks * 2304;
        for (int i = tid; i < 4608; i += 512) {
            int r = i / 288, o = i - r * 288;          // 288 uint4 per row
            *(uint4*)&sA[r * AS + o * 8] = *(const uint4*)(src + (size_t)r * 9216 + o * 8);
        }
    }
    __syncthreads();

    const bf16x8* bbase = (const bf16x8*)fc1wqF + (size_t)(ks * 72 + wave * 9) * 64 + lane;
    const u16* abase = &sA[row * AS + wave * 288 + quad * 8];
    f32x4 acc[8];
#pragma unroll
    for (int nt = 0; nt < 8; ++nt) acc[nt] = f32x4{0.f, 0.f, 0.f, 0.f};
#pragma unroll 1
    for (int k2 = 0; k2 < 9; ++k2) {
        bf16x8 a = *(const bf16x8*)(abase + k2 * 32);  // ds_read_b128, free 2-way banks
        bf16x8 b[8];
#pragma unroll
        for (int nt = 0; nt < 8; ++nt)
            b[nt] = bbase[((size_t)nt * 288 + k2) * 64];  // dense 1 KB wave-load
#pragma unroll
        for (int nt = 0; nt < 8; ++nt)
            acc[nt] = __builtin_amdgcn_mfma_f32_16x16x32_bf16(a, b[nt], acc[nt], 0, 0, 0);
    }
    __syncthreads();   // all ds_reads of sA done; safe to reuse smem as sAcc
    if (wave < 4) {
#pragma unroll
        for (int nt = 0; nt < 8; ++nt)
#pragma unroll
            for (int r = 0; r < 4; ++r)
                sAcc[wave * 2112 + (quad * 4 + r) * 132 + nt * 16 + row] = acc[nt][r];
    }
    __syncthreads();
    if (wave >= 4) {
#pragma unroll
        for (int nt = 0; nt < 8; ++nt)
#pragma unroll
            for (int r = 0; r < 4; ++r)
                sAcc[(wave - 4) * 2112 + (quad * 4 + r) * 132 + nt * 16 + row] += acc[nt][r];
    }
    __syncthreads();
    for (int e = tid; e < 2048; e += 512) {
        int o = (e >> 7) * 132 + (e & 127);
        part[(size_t)blk * 2048 + e] = sAcc[o] + sAcc[2112 + o] + sAcc[4224 + o] + sAcc[6336 + o];
    }
}

// ---------- kernel 3b: reduce K-partials + bias + relu + pq, fused fc2 ----------
__global__ __launch_bounds__(256) void fc2_red_kernel(const float* __restrict__ part,
    const float* __restrict__ fc1b, const float* __restrict__ fc2wq,
    const float* __restrict__ fc2b, float* __restrict__ out) {
    __shared__ __align__(16) u16 sFc1[2048];
    __shared__ float sW2[1280];
    __shared__ float sB2[16];
    __shared__ float sLut[256];
    int mb = blockIdx.x, tid = threadIdx.x;
    lut_init(tid, sLut);
    for (int i = tid; i < 1280; i += 256) sW2[i] = fc2wq[i];
    if (tid < 10) sB2[tid] = fc2b[tid];
    __syncthreads();
    const float* pb = part + (size_t)mb * 4 * 2048;
    for (int e = tid; e < 2048; e += 256) {
        float s = pb[e] + pb[2048 + e] + pb[4096 + e] + pb[6144 + e];
        sFc1[e] = (u16)(pq_pos_raw(fmaxf(s + fc1b[e & 127], 0.f), sLut) >> 16);
    }
    __syncthreads();
    if (tid < 160) {
        int il = tid / 10, oc = tid - il * 10;
        float s = sB2[oc];
        const u16* hp = &sFc1[il * 128];
        const float* wp = &sW2[oc * 128];
#pragma unroll
        for (int k = 0; k < 128; ++k) s = fmaf(b2f(hp[k]), wp[k], s);
        out[(size_t)(mb * 16 + il) * 10 + oc] = s;
    }
}

extern "C" void kernel_launch(void* const* d_in, const int* in_sizes, int n_in,
                              void* d_out, int out_size, void* d_ws, size_t ws_size,
                              hipStream_t stream) {
    const float* x    = (const float*)d_in[0];
    const float* w1   = (const float*)d_in[1];
    const float* b1   = (const float*)d_in[2];
    const float* w2   = (const float*)d_in[3];
    const float* b2   = (const float*)d_in[4];
    const float* fw1  = (const float*)d_in[5];
    const float* fb1  = (const float*)d_in[6];
    const float* fw2  = (const float*)d_in[7];
    const float* fb2  = (const float*)d_in[8];
    float* out = (float*)d_out;

    char* ws = (char*)d_ws;
    float* w1q     = (float*)(ws + 0);           // 1152 B
    float* fc2wq   = (float*)(ws + 1280);        // 5120 B
    u16*   w2frag  = (u16*)(ws + 6400);          // 36864 B
    u16*   fc1wqF  = (u16*)(ws + 43520);         // 2359296 B, frag-linear
    u16*   pooled  = (u16*)(ws + 2402816);       // 75497472 B, [img][c*144 + y*12 + x] bf16
    float* part    = (float*)(ws + 77900288);    // 8388608 B, [mb*4+ks][16*128] f32
    // total ~86.3 MB

    prep_kernel<<<72, 256, 0, stream>>>(w1, w2, fw2, w1q, w2frag, fc2wq);
    prep2_kernel<<<4608, 256, 0, stream>>>(fw1, fc1wqF);
    conv_fused_kernel<<<4096, 512, 0, stream>>>(x, w1q, b1, w2frag, b2, pooled);
    fc1_part_kernel<<<1024, 512, 0, stream>>>(pooled, fc1wqF, part);
    fc2_red_kernel<<<256, 256, 0, stream>>>(part, fb1, fc2wq, fb2, out);
}

// Round 13
// 249.619 us; speedup vs baseline: 1.1414x; 1.1414x over previous
//
#include <hip/hip_runtime.h>

using u16 = unsigned short;
using u32 = unsigned int;
typedef __attribute__((ext_vector_type(8))) short bf16x8;
typedef __attribute__((ext_vector_type(4))) float f32x4;

// ---------- posit(8,1) round-to-nearest (float core, verified bit-exact on HW) ----------
__device__ __forceinline__ float posit_q(float x) {
    float a = __builtin_fabsf(x);
    u32 u = __float_as_uint(a);
    int logx = (int)(u >> 23) - 127;
    logx = logx < -60 ? -60 : (logx > 60 ? 60 : logx);
    float frac = __uint_as_float((u & 0x007fffffu) | 0x3f800000u);  // [1,2)
    int k = logx >> 1;                            // floor(logx/2), es=1
    int rl = (k >= 0) ? (k + 2) : (1 - k);        // regime length
    int fb = 6 - rl; fb = fb < 0 ? 0 : fb;        // fraction bits, <=4
    float step = (float)(1 << fb);
    float q = rintf(frac * step) * __uint_as_float((u32)(127 + logx - fb) << 23);
    q = fminf(fmaxf(q, 0x1p-12f), 0x1p12f);
    return (a > 0.0f) ? copysignf(q, x) : 0.0f;
}

__device__ __forceinline__ float b2f(u16 v) { return __uint_as_float((u32)v << 16); }
__device__ __forceinline__ u16 f2b(float f) { return (u16)(__float_as_uint(f) >> 16); }  // exact for posit values

// ---------- Dekker-LUT posit quantizer (exact RNE onto the posit grid; verified R8) ----------
__device__ __forceinline__ void lut_init(int tid, float* lut) {
    if (tid < 256) {
        int e = tid - 127;
        float m = 0.f;
        if (e >= -12 && e <= 12) {
            int k = e >> 1;
            int rl = max(k + 2, 1 - k);
            int fb = max(6 - rl, 0);
            m = __uint_as_float((u32)(150 + e - fb) << 23) * 1.5f;  // 1.5*2^(23+e-fb)
        }
        lut[tid] = m;
    }
}
__device__ __forceinline__ u32 pq_pos_raw(float x, const float* __restrict__ lut) {  // x >= 0
    u32 u = __float_as_uint(x);
    float c = lut[u >> 23];
    float q = (x + c) - c;
    q = fminf(fmaxf(q, 0x1p-12f), 0x1p12f);
    return u == 0u ? 0u : __float_as_uint(q);
}

// ---------- kernel 1: quantize small weights (w1, w2frag, fc2) ----------
__global__ __launch_bounds__(256) void prep_kernel(
    const float* __restrict__ w1, const float* __restrict__ w2,
    const float* __restrict__ fw2,
    float* __restrict__ w1q, u16* __restrict__ w2frag, float* __restrict__ fc2wq) {
    int i = blockIdx.x * 256 + threadIdx.x;
    if (i < 288)  w1q[i]   = posit_q(w1[i]);
    if (i < 1280) fc2wq[i] = posit_q(fw2[i]);
    if (i < 18432) {
        int e = i & 7, lane = (i >> 3) & 63, c9 = i >> 9;
        int kc = c9 % 9, nt = c9 / 9;
        int n = nt * 16 + (lane & 15);
        int ci = ((lane >> 4) << 3) + e;
        w2frag[i] = f2b(posit_q(w2[n * 288 + ci * 9 + kc]));  // w2 flat [n][ci][kh][kw]
    }
}

// ---------- kernel 1b: quantize fc1 weights into FRAG-LINEAR layout ----------
// fc1wqF[nt(8)][kk(288)][lane(64)][e(8)]: holds pq(fw1)[n][k], n = nt*16 + (lane&15),
// k = kk*32 + (lane>>4)*8 + e  -> fc1_part B-loads become dense 1 KB wave-loads.
__global__ __launch_bounds__(256) void prep2_kernel(
    const float* __restrict__ fw1, u16* __restrict__ fc1wqF) {
    int i = blockIdx.x * 256 + threadIdx.x;       // grid exactly covers 1179648
    int e = i & 7, lane = (i >> 3) & 63, c = i >> 9;
    int kk = c % 288, nt = c / 288;
    int n = nt * 16 + (lane & 15);
    int k = kk * 32 + ((lane >> 4) << 3) + e;
    fc1wqF[i] = f2b(posit_q(fw1[(size_t)n * 9216 + k]));
}

// ---------- kernel 2: fused pq(x) + conv1 + relu + pq + conv2(MFMA) + pool + bias + relu + pq ----------
// BYTE-EXACT R11 text (stable fingerprint: 146 us, VGPR 52, hbm 87 MB across R8/R10/R11).
// NOTE: the phase-0 fc1wq write is LOAD-BEARING for the compiler's allocation — removing it in R12
// flipped scheduling into scratch-spill (VGPR 64, 600 MB HBM, 186 us). It now targets a dummy region.
#define PLS 5416
__global__ __launch_bounds__(512, 4) void conv_fused_kernel(
    const float* __restrict__ x, const float* __restrict__ w1q, const float* __restrict__ b1,
    const u16* __restrict__ w2frag, const float* __restrict__ b2,
    const float* __restrict__ fw1, u16* __restrict__ fc1wq, u16* __restrict__ pooled) {
    __shared__ __align__(16) float sX[784];           // 3136 B
    __shared__ __align__(16) u16 sH1[4 * PLS];        // 43328 B
    __shared__ __align__(16) u16 sPool[64 * 152];     // 19456 B
    __shared__ float sLut[256];                       // 1024 B (total ~67 KB -> 2 blocks/CU)
    int img = blockIdx.x, tid = threadIdx.x;
    int wave = tid >> 6, lane = tid & 63;
    int col = lane & 15, quad = lane >> 4;

    lut_init(tid, sLut);

    // phase 0: pq input image -> LDS; also quantize this block's slice of fc1 weights (global)
    for (int i = tid; i < 784; i += 512) sX[i] = posit_q(x[(size_t)img * 784 + i]);
    if (tid < 288) fc1wq[(size_t)img * 288 + tid] = f2b(posit_q(fw1[(size_t)img * 288 + tid]));

    // conv1 weights for this thread's oc pair (registers)
    int ocp = tid & 15;
    float wreg[18];
#pragma unroll
    for (int j = 0; j < 18; ++j) wreg[j] = w1q[ocp * 18 + j];
    float bias0 = b1[ocp * 2], bias1 = b1[ocp * 2 + 1];

    __syncthreads();

    // phase 1: conv1 (+bias+relu+pq) -> sH1 planes. thread = (pgrp = tid>>4 in 0..31, ocp).
    int pgrp = tid >> 4;
    u16* h1dst = &sH1[(ocp >> 2) * PLS + 2 * (ocp & 3)];
    for (int it = 0; it < 22; ++it) {
        int p = it * 32 + pgrp;
        if (p < 676) {
            int y = p / 26, xx = p - y * 26;
            const float* px = &sX[y * 28 + xx];
            float in9[9];
#pragma unroll
            for (int r = 0; r < 3; ++r)
#pragma unroll
                for (int c = 0; c < 3; ++c) in9[r * 3 + c] = px[r * 28 + c];
            float a0 = bias0, a1 = bias1;
#pragma unroll
            for (int j = 0; j < 9; ++j) {
                a0 = fmaf(wreg[j], in9[j], a0);
                a1 = fmaf(wreg[9 + j], in9[j], a1);
            }
            u32 r0 = pq_pos_raw(fmaxf(a0, 0.f), sLut);
            u32 r1 = pq_pos_raw(fmaxf(a1, 0.f), sLut);
            *(u32*)&h1dst[p * 8] = (r0 >> 16) | (r1 & 0xFFFF0000u);
        }
    }

    // conv2 B-frags for this wave's n-pair
    __syncthreads();
    int npair = wave & 1, mq = wave >> 1;
    bf16x8 bfrag[2][9];
#pragma unroll
    for (int j = 0; j < 2; ++j)
#pragma unroll
        for (int kc = 0; kc < 9; ++kc)
            bfrag[j][kc] = *(const bf16x8*)(w2frag + (((npair * 2 + j) * 9 + kc) * 64 + lane) * 8);
    float cb0 = b2[(npair * 2) * 16 + col];
    float cb1 = b2[(npair * 2 + 1) * 16 + col];
    int poolb0 = ((npair * 2) * 16 + col) * 152;
    int poolb1 = ((npair * 2 + 1) * 16 + col) * 152;
    const u16* aplane = &sH1[quad * PLS];

    // phase 2: conv2 MFMA + pool(max) + bias + relu + pq. Wave: m-tiles mq*9..mq*9+8, 2 n-tiles.
    for (int t = 0; t < 9; ++t) {
        int mt = mq * 9 + t;
        int m = mt * 16 + col;                  // pool-permuted m (A-row = lane&15)
        int pp = m >> 2, wi = m & 3;
        int py = pp / 12, px_ = pp - py * 12;
        int oh = 2 * py + (wi >> 1), ow = 2 * px_ + (wi & 1);
        const u16* ap = aplane + (oh * 26 + ow) * 8;
        f32x4 acc0 = {0.f, 0.f, 0.f, 0.f}, acc1 = {0.f, 0.f, 0.f, 0.f};
#pragma unroll
        for (int kc = 0; kc < 9; ++kc) {
            int kh = kc / 3, kw = kc - kh * 3;
            bf16x8 af = *(const bf16x8*)(ap + (kh * 26 + kw) * 8);
            acc0 = __builtin_amdgcn_mfma_f32_16x16x32_bf16(af, bfrag[0][kc], acc0, 0, 0, 0);
            acc1 = __builtin_amdgcn_mfma_f32_16x16x32_bf16(af, bfrag[1][kc], acc1, 0, 0, 0);
        }
        // C/D: row = quad*4+reg -> lane's 4 regs = one 2x2 pool window; max commutes exactly
        float mx0 = fmaxf(fmaxf(acc0[0], acc0[1]), fmaxf(acc0[2], acc0[3]));
        float mx1 = fmaxf(fmaxf(acc1[0], acc1[1]), fmaxf(acc1[2], acc1[3]));
        sPool[poolb0 + mt * 4 + quad] = (u16)(pq_pos_raw(fmaxf(mx0 + cb0, 0.f), sLut) >> 16);
        sPool[poolb1 + mt * 4 + quad] = (u16)(pq_pos_raw(fmaxf(mx1 + cb1, 0.f), sLut) >> 16);
    }
    __syncthreads();

    // phase 3: coalesced writeout, c-major (fc1 K layout)
    for (int u = tid; u < 1152; u += 512) {
        int c = u / 18, g = u - c * 18;
        uint4 v = *(const uint4*)&sPool[c * 152 + g * 8];
        *(uint4*)(pooled + (size_t)img * 9216 + c * 144 + g * 8) = v;
    }
}

// ---------- kernel 3a: fc1 partial GEMM, K split 4 ways — all-coalesced v2 (R12) ----------
// A staged to LDS (coalesced uint4, frags via ds_read_b128, row stride 2328 u16: 16B-aligned,
// 2-lanes/bank = free); B from frag-linear fc1wqF (dense 1 KB wave-loads). sAcc unioned over sA.
#define AS 2328
__global__ __launch_bounds__(512, 4) void fc1_part_kernel(const u16* __restrict__ pooled,
    const u16* __restrict__ fc1wqF, float* __restrict__ part) {
    __shared__ __align__(16) char smem[16 * AS * 2];   // 74496 B -> 2 blocks/CU
    u16* sA = (u16*)smem;
    float* sAcc = (float*)smem;                        // reused AFTER barrier (16*132*4 floats = 33792 B)
    int blk = blockIdx.x, tid = threadIdx.x;
    int mb = blk >> 2, ks = blk & 3;
    int wave = tid >> 6, lane = tid & 63;
    int row = lane & 15, quad = lane >> 4;

    // stage A-tile: rows mb*16..+15, K-slice ks*2304..+2303 (73728 B, fully coalesced)
    {
        const u16* src = pooled + (size_t)mb * 16 * 9216 + ks * 2304;
        for (int i = tid; i < 4608; i += 512) {
            int r = i / 288, o = i - r * 288;          // 288 uint4 per row
            *(uint4*)&sA[r * AS + o * 8] = *(const uint4*)(src + (size_t)r * 9216 + o * 8);
        }
    }
    __syncthreads();

    const bf16x8* bbase = (const bf16x8*)fc1wqF + (size_t)(ks * 72 + wave * 9) * 64 + lane;
    const u16* abase = &sA[row * AS + wave * 288 + quad * 8];
    f32x4 acc[8];
#pragma unroll
    for (int nt = 0; nt < 8; ++nt) acc[nt] = f32x4{0.f, 0.f, 0.f, 0.f};
#pragma unroll 1
    for (int k2 = 0; k2 < 9; ++k2) {
        bf16x8 a = *(const bf16x8*)(abase + k2 * 32);  // ds_read_b128, free 2-way banks
        bf16x8 b[8];
#pragma unroll
        for (int nt = 0; nt < 8; ++nt)
            b[nt] = bbase[((size_t)nt * 288 + k2) * 64];  // dense 1 KB wave-load
#pragma unroll
        for (int nt = 0; nt < 8; ++nt)
            acc[nt] = __builtin_amdgcn_mfma_f32_16x16x32_bf16(a, b[nt], acc[nt], 0, 0, 0);
    }
    __syncthreads();   // all ds_reads of sA done; safe to reuse smem as sAcc
    if (wave < 4) {
#pragma unroll
        for (int nt = 0; nt < 8; ++nt)
#pragma unroll
            for (int r = 0; r < 4; ++r)
                sAcc[wave * 2112 + (quad * 4 + r) * 132 + nt * 16 + row] = acc[nt][r];
    }
    __syncthreads();
    if (wave >= 4) {
#pragma unroll
        for (int nt = 0; nt < 8; ++nt)
#pragma unroll
            for (int r = 0; r < 4; ++r)
                sAcc[(wave - 4) * 2112 + (quad * 4 + r) * 132 + nt * 16 + row] += acc[nt][r];
    }
    __syncthreads();
    for (int e = tid; e < 2048; e += 512) {
        int o = (e >> 7) * 132 + (e & 127);
        part[(size_t)blk * 2048 + e] = sAcc[o] + sAcc[2112 + o] + sAcc[4224 + o] + sAcc[6336 + o];
    }
}

// ---------- kernel 3b: reduce K-partials + bias + relu + pq, fused fc2 ----------
__global__ __launch_bounds__(256) void fc2_red_kernel(const float* __restrict__ part,
    const float* __restrict__ fc1b, const float* __restrict__ fc2wq,
    const float* __restrict__ fc2b, float* __restrict__ out) {
    __shared__ __align__(16) u16 sFc1[2048];
    __shared__ float sW2[1280];
    __shared__ float sB2[16];
    __shared__ float sLut[256];
    int mb = blockIdx.x, tid = threadIdx.x;
    lut_init(tid, sLut);
    for (int i = tid; i < 1280; i += 256) sW2[i] = fc2wq[i];
    if (tid < 10) sB2[tid] = fc2b[tid];
    __syncthreads();
    const float* pb = part + (size_t)mb * 4 * 2048;
    for (int e = tid; e < 2048; e += 256) {
        float s = pb[e] + pb[2048 + e] + pb[4096 + e] + pb[6144 + e];
        sFc1[e] = (u16)(pq_pos_raw(fmaxf(s + fc1b[e & 127], 0.f), sLut) >> 16);
    }
    __syncthreads();
    if (tid < 160) {
        int il = tid / 10, oc = tid - il * 10;
        float s = sB2[oc];
        const u16* hp = &sFc1[il * 128];
        const float* wp = &sW2[oc * 128];
#pragma unroll
        for (int k = 0; k < 128; ++k) s = fmaf(b2f(hp[k]), wp[k], s);
        out[(size_t)(mb * 16 + il) * 10 + oc] = s;
    }
}

extern "C" void kernel_launch(void* const* d_in, const int* in_sizes, int n_in,
                              void* d_out, int out_size, void* d_ws, size_t ws_size,
                              hipStream_t stream) {
    const float* x    = (const float*)d_in[0];
    const float* w1   = (const float*)d_in[1];
    const float* b1   = (const float*)d_in[2];
    const float* w2   = (const float*)d_in[3];
    const float* b2   = (const float*)d_in[4];
    const float* fw1  = (const float*)d_in[5];
    const float* fb1  = (const float*)d_in[6];
    const float* fw2  = (const float*)d_in[7];
    const float* fb2  = (const float*)d_in[8];
    float* out = (float*)d_out;

    char* ws = (char*)d_ws;
    float* w1q     = (float*)(ws + 0);           // 1152 B
    float* fc2wq   = (float*)(ws + 1280);        // 5120 B
    u16*   w2frag  = (u16*)(ws + 6400);          // 36864 B
    u16*   fc1wqF  = (u16*)(ws + 43520);         // 2359296 B, frag-linear (read by fc1_part)
    u16*   fc1dmy  = (u16*)(ws + 2402816);       // 2359296 B, k-linear DUMMY (kept for conv_fused's
                                                 //            allocation-stable phase-0 write; unread)
    u16*   pooled  = (u16*)(ws + 4762112);       // 75497472 B, [img][c*144 + y*12 + x] bf16
    float* part    = (float*)(ws + 80259584);    // 8388608 B, [mb*4+ks][16*128] f32
    // total ~88.6 MB

    prep_kernel<<<72, 256, 0, stream>>>(w1, w2, fw2, w1q, w2frag, fc2wq);
    prep2_kernel<<<4608, 256, 0, stream>>>(fw1, fc1wqF);
    conv_fused_kernel<<<4096, 512, 0, stream>>>(x, w1q, b1, w2frag, b2, fw1, fc1dmy, pooled);
    fc1_part_kernel<<<1024, 512, 0, stream>>>(pooled, fc1wqF, part);
    fc2_red_kernel<<<256, 256, 0, stream>>>(part, fb1, fc2wq, fb2, out);
}